// Round 3
// baseline (435.928 us; speedup 1.0000x reference)
//
#include <hip/hip_runtime.h>
#include <stdint.h>

#define N_NODES 100000
#define N_EDGES 1600000
#define IN_F 128
#define OUT_F 32

#define RB 256                    // rows per bucket (pow2, shift 8)
#define NB 391                    // ceil(N_NODES / RB)
#define ABLK 256                  // phase-A blocks
#define EPA (N_EDGES / ABLK)      // 6250 edges per phase-A block (exact)
#define NTOT (NB * ABLK)          // 100096
#define CHUNK (NTOT / 256)        // 391 elements per scan thread (exact)

// ---------------------------------------------------------------------------
// GEMM: support = x @ W   [N,128]x[128,32] -> [N,32]  (unchanged from r2)
// ---------------------------------------------------------------------------
__global__ __launch_bounds__(256) void gcn_gemm2(const float* __restrict__ x,
                                                 const float* __restrict__ w,
                                                 float* __restrict__ support) {
    __shared__ float ws[IN_F][OUT_F];      // 16 KB
    __shared__ float xs[64][IN_F + 4];     // stride 132 floats
    const int tid = threadIdx.x;
    const int rowBase = blockIdx.x * 64;

    {
        float* wsf = &ws[0][0];
        #pragma unroll
        for (int chunk = 0; chunk < 4; ++chunk) {
            const int i = chunk * 1024 + tid * 4;
            *reinterpret_cast<float4*>(wsf + i) =
                *reinterpret_cast<const float4*>(&w[i]);
        }
    }
    #pragma unroll
    for (int chunk = 0; chunk < 8; ++chunk) {
        const int idx = chunk * 1024 + tid * 4;
        const int r = idx >> 7;
        const int c = idx & 127;
        if (rowBase + r < N_NODES) {
            *reinterpret_cast<float4*>(&xs[r][c]) =
                *reinterpret_cast<const float4*>(&x[(size_t)(rowBase + r) * IN_F + c]);
        }
    }
    __syncthreads();

    const int fg = tid & 7;
    const int rg = tid >> 3;
    const int f0 = fg * 4;
    const int r0 = rg * 2;

    float acc[2][4] = {{0.f, 0.f, 0.f, 0.f}, {0.f, 0.f, 0.f, 0.f}};
    for (int k0 = 0; k0 < IN_F; k0 += 4) {
        const float4 xa = *reinterpret_cast<const float4*>(&xs[r0][k0]);
        const float4 xb = *reinterpret_cast<const float4*>(&xs[r0 + 1][k0]);
        const float xav[4] = {xa.x, xa.y, xa.z, xa.w};
        const float xbv[4] = {xb.x, xb.y, xb.z, xb.w};
        #pragma unroll
        for (int j = 0; j < 4; ++j) {
            const float4 wv = *reinterpret_cast<const float4*>(&ws[k0 + j][f0]);
            acc[0][0] += xav[j] * wv.x;  acc[0][1] += xav[j] * wv.y;
            acc[0][2] += xav[j] * wv.z;  acc[0][3] += xav[j] * wv.w;
            acc[1][0] += xbv[j] * wv.x;  acc[1][1] += xbv[j] * wv.y;
            acc[1][2] += xbv[j] * wv.z;  acc[1][3] += xbv[j] * wv.w;
        }
    }
    #pragma unroll
    for (int i = 0; i < 2; ++i) {
        const int row = rowBase + r0 + i;
        if (row < N_NODES) {
            float4 v;
            v.x = acc[i][0]; v.y = acc[i][1]; v.z = acc[i][2]; v.w = acc[i][3];
            *reinterpret_cast<float4*>(&support[(size_t)row * OUT_F + f0]) = v;
        }
    }
}

// ---------------------------------------------------------------------------
// Phase A1: per-block bucket histogram. count laid out k-major: count[k*ABLK+b]
// ---------------------------------------------------------------------------
__global__ __launch_bounds__(256) void gcn_count(const int* __restrict__ row,
                                                 int* __restrict__ count) {
    __shared__ int h[NB];
    const int tid = threadIdx.x, b = blockIdx.x;
    for (int i = tid; i < NB; i += 256) h[i] = 0;
    __syncthreads();
    const int e0 = b * EPA;
    for (int i = tid; i < EPA; i += 256)
        atomicAdd(&h[row[e0 + i] >> 8], 1);
    __syncthreads();
    for (int i = tid; i < NB; i += 256)
        count[i * ABLK + b] = h[i];
}

// ---------------------------------------------------------------------------
// Exclusive scan of the flat 100096-entry count matrix (one block).
// ---------------------------------------------------------------------------
__global__ __launch_bounds__(256) void gcn_scan(const int* __restrict__ count,
                                                int* __restrict__ ptr) {
    __shared__ int s[256];
    const int t = threadIdx.x;
    const int base = t * CHUNK;
    int sum = 0;
    for (int j = 0; j < CHUNK; ++j) sum += count[base + j];
    s[t] = sum;
    __syncthreads();
    for (int off = 1; off < 256; off <<= 1) {
        const int v = (t >= off) ? s[t - off] : 0;
        __syncthreads();
        s[t] += v;
        __syncthreads();
    }
    int p = s[t] - sum;   // exclusive prefix of this chunk
    for (int j = 0; j < CHUNK; ++j) {
        ptr[base + j] = p;
        p += count[base + j];
    }
}

// ---------------------------------------------------------------------------
// Phase A2: bin edges. Each (block,bucket) segment is contiguous in rec[].
// Record: lo32 = col | (row_local << 17), hi32 = val bits.  (col<2^17, rl<2^8)
// ---------------------------------------------------------------------------
__global__ __launch_bounds__(256) void gcn_bin(const int* __restrict__ row,
                                               const int* __restrict__ col,
                                               const float* __restrict__ val,
                                               const int* __restrict__ ptr,
                                               long long* __restrict__ rec) {
    __shared__ int cur[NB];
    const int tid = threadIdx.x, b = blockIdx.x;
    for (int i = tid; i < NB; i += 256) cur[i] = ptr[i * ABLK + b];
    __syncthreads();
    const int e0 = b * EPA;
    for (int i = tid; i < EPA; i += 256) {
        const int e = e0 + i;
        const int r = row[e];
        const int k = r >> 8;
        const int slot = atomicAdd(&cur[k], 1);
        const uint32_t lo = (uint32_t)col[e] | ((uint32_t)(r & 255) << 17);
        const uint64_t hi = (uint64_t)__float_as_uint(val[e]);
        rec[slot] = (long long)((hi << 32) | (uint64_t)lo);
    }
}

// ---------------------------------------------------------------------------
// Phase B: one block per bucket. LDS fp32 accumulate (lane->feature->bank
// identity: conflict-free), then single write of out with bias fused.
// ---------------------------------------------------------------------------
__global__ __launch_bounds__(256) void gcn_acc(const int* __restrict__ ptr,
                                               const long long* __restrict__ rec,
                                               const float* __restrict__ support,
                                               const float* __restrict__ bias,
                                               float* __restrict__ out) {
    __shared__ float acc[RB * OUT_F];   // 32 KB
    const int tid = threadIdx.x, k = blockIdx.x;
    #pragma unroll
    for (int i = tid; i < (RB * OUT_F) / 4; i += 256) {
        float4 z; z.x = 0.f; z.y = 0.f; z.z = 0.f; z.w = 0.f;
        *reinterpret_cast<float4*>(&acc[i * 4]) = z;
    }
    __syncthreads();

    const int start = ptr[k * ABLK];
    const int end = (k < NB - 1) ? ptr[(k + 1) * ABLK] : N_EDGES;
    const int f = tid & 31;
    for (int i = start + (tid >> 5); i < end; i += 8) {
        const uint64_t pk = (uint64_t)rec[i];      // wave-broadcast 8B
        const int c  = (int)(pk & 0x1ffff);
        const int rl = (int)((pk >> 17) & 0xff);
        const float v = __uint_as_float((uint32_t)(pk >> 32));
        atomicAdd(&acc[rl * OUT_F + f], v * support[(size_t)c * OUT_F + f]);
    }
    __syncthreads();

    const int rowBase = k * RB;
    const int rb = min(RB, N_NODES - rowBase);
    for (int idx = tid; idx < rb * OUT_F; idx += 256)
        out[(size_t)rowBase * OUT_F + idx] = acc[idx] + bias[idx & 31];
}

// ---------------------------------------------------------------------------
// Fallback path (ws too small): round-1 atomic scatter
// ---------------------------------------------------------------------------
__global__ __launch_bounds__(256) void gcn_bias_init(const float* __restrict__ bias,
                                                     float* __restrict__ out) {
    const int i = blockIdx.x * 256 + threadIdx.x;
    if (i < N_NODES * OUT_F) out[i] = bias[i & 31];
}

__global__ __launch_bounds__(256) void gcn_scatter(const int* __restrict__ row,
                                                   const int* __restrict__ col,
                                                   const float* __restrict__ val,
                                                   const float* __restrict__ support,
                                                   float* __restrict__ out) {
    const int f = threadIdx.x & 31;
    const int grp = threadIdx.x >> 5;
    long long e = (long long)blockIdx.x * 8 + grp;
    const long long stride = (long long)gridDim.x * 8;
    for (; e < N_EDGES; e += stride) {
        const int r = row[e];
        const int c = col[e];
        const float v = val[e];
        const float s = support[(size_t)c * OUT_F + f];
        atomicAdd(&out[(size_t)r * OUT_F + f], v * s);
    }
}

extern "C" void kernel_launch(void* const* d_in, const int* in_sizes, int n_in,
                              void* d_out, int out_size, void* d_ws, size_t ws_size,
                              hipStream_t stream) {
    const float* x       = (const float*)d_in[0];
    const int*   adj_row = (const int*)d_in[1];
    const int*   adj_col = (const int*)d_in[2];
    const float* adj_val = (const float*)d_in[3];
    const float* weight  = (const float*)d_in[4];
    const float* bias    = (const float*)d_in[5];
    float* out = (float*)d_out;

    char* ws = (char*)d_ws;
    const size_t SUPPORT_B = (size_t)N_NODES * OUT_F * 4;     // 12,800,000
    const size_t REC_B     = (size_t)N_EDGES * 8;             // 12,800,000
    const size_t CNT_B     = ((size_t)NTOT * 4 + 255) & ~(size_t)255;  // ~400,640
    const size_t NEED = SUPPORT_B + REC_B + 2 * CNT_B;

    float* support  = (float*)(ws);
    long long* rec  = (long long*)(ws + SUPPORT_B);
    int* count      = (int*)(ws + SUPPORT_B + REC_B);
    int* ptr        = (int*)(ws + SUPPORT_B + REC_B + CNT_B);

    // 1) support = x @ W
    gcn_gemm2<<<(N_NODES + 63) / 64, 256, 0, stream>>>(x, weight, support);

    if (ws_size >= NEED) {
        // 2) blocked multisplit: count -> scan -> bin
        gcn_count<<<ABLK, 256, 0, stream>>>(adj_row, count);
        gcn_scan<<<1, 256, 0, stream>>>(count, ptr);
        gcn_bin<<<ABLK, 256, 0, stream>>>(adj_row, adj_col, adj_val, ptr, rec);
        // 3) per-bucket LDS accumulation, bias fused, single out write
        gcn_acc<<<NB, 256, 0, stream>>>(ptr, rec, support, bias, out);
    } else {
        // Fallback: atomic scatter path
        gcn_bias_init<<<(N_NODES * OUT_F + 255) / 256, 256, 0, stream>>>(bias, out);
        gcn_scatter<<<8192, 256, 0, stream>>>(adj_row, adj_col, adj_val, support, out);
    }
}

// Round 4
// 401.340 us; speedup vs baseline: 1.0862x; 1.0862x over previous
//
#include <hip/hip_runtime.h>
#include <stdint.h>

#define N_NODES 100000
#define N_EDGES 1600000
#define IN_F 128
#define OUT_F 32

#define RB 128                    // rows per bucket (shift 7)
#define NB 782                    // ceil(N_NODES / RB)
#define ABLK 256                  // phase-A blocks
#define EPA (N_EDGES / ABLK)      // 6250 edges per phase-A block (exact)
#define NTOT (NB * ABLK)          // 200192 = 782 * 256
#define NBLK_SCAN (NTOT / 256)    // 782 (exact)

// ---------------------------------------------------------------------------
// GEMM: support = x @ W   [N,128]x[128,32] -> [N,32]  (unchanged, known-good)
// ---------------------------------------------------------------------------
__global__ __launch_bounds__(256) void gcn_gemm2(const float* __restrict__ x,
                                                 const float* __restrict__ w,
                                                 float* __restrict__ support) {
    __shared__ float ws[IN_F][OUT_F];      // 16 KB
    __shared__ float xs[64][IN_F + 4];     // stride 132 floats
    const int tid = threadIdx.x;
    const int rowBase = blockIdx.x * 64;

    {
        float* wsf = &ws[0][0];
        #pragma unroll
        for (int chunk = 0; chunk < 4; ++chunk) {
            const int i = chunk * 1024 + tid * 4;
            *reinterpret_cast<float4*>(wsf + i) =
                *reinterpret_cast<const float4*>(&w[i]);
        }
    }
    #pragma unroll
    for (int chunk = 0; chunk < 8; ++chunk) {
        const int idx = chunk * 1024 + tid * 4;
        const int r = idx >> 7;
        const int c = idx & 127;
        if (rowBase + r < N_NODES) {
            *reinterpret_cast<float4*>(&xs[r][c]) =
                *reinterpret_cast<const float4*>(&x[(size_t)(rowBase + r) * IN_F + c]);
        }
    }
    __syncthreads();

    const int fg = tid & 7;
    const int rg = tid >> 3;
    const int f0 = fg * 4;
    const int r0 = rg * 2;

    float acc[2][4] = {{0.f, 0.f, 0.f, 0.f}, {0.f, 0.f, 0.f, 0.f}};
    for (int k0 = 0; k0 < IN_F; k0 += 4) {
        const float4 xa = *reinterpret_cast<const float4*>(&xs[r0][k0]);
        const float4 xb = *reinterpret_cast<const float4*>(&xs[r0 + 1][k0]);
        const float xav[4] = {xa.x, xa.y, xa.z, xa.w};
        const float xbv[4] = {xb.x, xb.y, xb.z, xb.w};
        #pragma unroll
        for (int j = 0; j < 4; ++j) {
            const float4 wv = *reinterpret_cast<const float4*>(&ws[k0 + j][f0]);
            acc[0][0] += xav[j] * wv.x;  acc[0][1] += xav[j] * wv.y;
            acc[0][2] += xav[j] * wv.z;  acc[0][3] += xav[j] * wv.w;
            acc[1][0] += xbv[j] * wv.x;  acc[1][1] += xbv[j] * wv.y;
            acc[1][2] += xbv[j] * wv.z;  acc[1][3] += xbv[j] * wv.w;
        }
    }
    #pragma unroll
    for (int i = 0; i < 2; ++i) {
        const int row = rowBase + r0 + i;
        if (row < N_NODES) {
            float4 v;
            v.x = acc[i][0]; v.y = acc[i][1]; v.z = acc[i][2]; v.w = acc[i][3];
            *reinterpret_cast<float4*>(&support[(size_t)row * OUT_F + f0]) = v;
        }
    }
}

// ---------------------------------------------------------------------------
// Phase A1: per-block bucket histogram. count[k*ABLK + b], k = row >> 7.
// ---------------------------------------------------------------------------
__global__ __launch_bounds__(256) void gcn_count(const int* __restrict__ row,
                                                 int* __restrict__ count) {
    __shared__ int h[NB];
    const int tid = threadIdx.x, b = blockIdx.x;
    for (int i = tid; i < NB; i += 256) h[i] = 0;
    __syncthreads();
    const int e0 = b * EPA;
    for (int i = tid; i < EPA; i += 256)
        atomicAdd(&h[row[e0 + i] >> 7], 1);
    __syncthreads();
    for (int i = tid; i < NB; i += 256)
        count[i * ABLK + b] = h[i];
}

// ---------------------------------------------------------------------------
// 3-phase exclusive scan over the flat NTOT count matrix.
// ---------------------------------------------------------------------------
__global__ __launch_bounds__(256) void scan_a(const int* __restrict__ count,
                                              int* __restrict__ ptr,
                                              int* __restrict__ bsum) {
    __shared__ int s[256];
    const int i = blockIdx.x * 256 + threadIdx.x;
    const int v = count[i];
    s[threadIdx.x] = v;
    __syncthreads();
    for (int off = 1; off < 256; off <<= 1) {
        const int t = (threadIdx.x >= off) ? s[threadIdx.x - off] : 0;
        __syncthreads();
        s[threadIdx.x] += t;
        __syncthreads();
    }
    ptr[i] = s[threadIdx.x] - v;
    if (threadIdx.x == 255) bsum[blockIdx.x] = s[255];
}

__global__ __launch_bounds__(1024) void scan_b(int* __restrict__ bsum) {
    __shared__ int s[1024];
    const int v = (threadIdx.x < NBLK_SCAN) ? bsum[threadIdx.x] : 0;
    s[threadIdx.x] = v;
    __syncthreads();
    for (int off = 1; off < 1024; off <<= 1) {
        const int t = (threadIdx.x >= off) ? s[threadIdx.x - off] : 0;
        __syncthreads();
        s[threadIdx.x] += t;
        __syncthreads();
    }
    if (threadIdx.x < NBLK_SCAN) bsum[threadIdx.x] = s[threadIdx.x] - v;  // exclusive
}

__global__ __launch_bounds__(256) void scan_c(int* __restrict__ ptr,
                                              const int* __restrict__ bsum) {
    const int i = blockIdx.x * 256 + threadIdx.x;
    ptr[i] += bsum[blockIdx.x];
}

// ---------------------------------------------------------------------------
// Phase A2: bin edges. (block,bucket) segments contiguous in rec[].
// Record: lo32 = col | (row_local << 17), hi32 = val bits.
// ---------------------------------------------------------------------------
__global__ __launch_bounds__(256) void gcn_bin(const int* __restrict__ row,
                                               const int* __restrict__ col,
                                               const float* __restrict__ val,
                                               const int* __restrict__ ptr,
                                               long long* __restrict__ rec) {
    __shared__ int cur[NB];
    const int tid = threadIdx.x, b = blockIdx.x;
    for (int i = tid; i < NB; i += 256) cur[i] = ptr[i * ABLK + b];
    __syncthreads();
    const int e0 = b * EPA;
    for (int i = tid; i < EPA; i += 256) {
        const int e = e0 + i;
        const int r = row[e];
        const int k = r >> 7;
        const int slot = atomicAdd(&cur[k], 1);
        const uint32_t lo = (uint32_t)col[e] | ((uint32_t)(r & 127) << 17);
        const uint64_t hi = (uint64_t)__float_as_uint(val[e]);
        rec[slot] = (long long)((hi << 32) | (uint64_t)lo);
    }
}

// ---------------------------------------------------------------------------
// Phase B v2: one block per 128-row bucket. Batch-8 prefetched accumulate
// into a 16 KB LDS tile, then single float4 write of out with bias fused.
// ---------------------------------------------------------------------------
__global__ __launch_bounds__(256) void gcn_acc(const int* __restrict__ ptr,
                                               const long long* __restrict__ rec,
                                               const float* __restrict__ support,
                                               const float* __restrict__ bias,
                                               float* __restrict__ out) {
    __shared__ float acc[RB * OUT_F];   // 16 KB
    const int tid = threadIdx.x, k = blockIdx.x;
    #pragma unroll
    for (int i = tid; i < (RB * OUT_F) / 4; i += 256) {
        float4 z; z.x = 0.f; z.y = 0.f; z.z = 0.f; z.w = 0.f;
        *reinterpret_cast<float4*>(&acc[i * 4]) = z;
    }
    __syncthreads();

    const int g = tid >> 5;          // edge-group 0..7
    const int f = tid & 31;          // feature lane
    const int start = ptr[k * ABLK];
    const int end = (k < NB - 1) ? ptr[(k + 1) * ABLK] : N_EDGES;
    const int span = end - start;
    const int nb64 = span >> 6;      // full 64-record chunks

    for (int b = 0; b < nb64; ++b) {
        const int base = start + b * 64 + g * 8;
        long long pk[8];
        #pragma unroll
        for (int j = 0; j < 8; ++j) pk[j] = rec[base + j];   // 8 broadcast loads
        float sv[8];
        int rl[8];
        float vv[8];
        #pragma unroll
        for (int j = 0; j < 8; ++j) {
            const int c = (int)((uint64_t)pk[j] & 0x1ffff);
            rl[j] = (int)(((uint64_t)pk[j] >> 17) & 0x7f);
            vv[j] = __uint_as_float((uint32_t)((uint64_t)pk[j] >> 32));
            sv[j] = support[(size_t)c * OUT_F + f];          // 8 independent gathers
        }
        #pragma unroll
        for (int j = 0; j < 8; ++j)
            atomicAdd(&acc[rl[j] * OUT_F + f], vv[j] * sv[j]);
    }
    // remainder (< 64 records)
    for (int i = start + nb64 * 64 + g; i < end; i += 8) {
        const uint64_t pk = (uint64_t)rec[i];
        const int c  = (int)(pk & 0x1ffff);
        const int rl1 = (int)((pk >> 17) & 0x7f);
        const float v = __uint_as_float((uint32_t)(pk >> 32));
        atomicAdd(&acc[rl1 * OUT_F + f], v * support[(size_t)c * OUT_F + f]);
    }
    __syncthreads();

    const int rowBase = k * RB;
    const int rb = min(RB, N_NODES - rowBase);
    const int n4 = (rb * OUT_F) / 4;
    for (int i = tid; i < n4; i += 256) {
        const float4 a = *reinterpret_cast<const float4*>(&acc[i * 4]);
        const float4 bv = *reinterpret_cast<const float4*>(&bias[(i * 4) & 31]);
        float4 o;
        o.x = a.x + bv.x; o.y = a.y + bv.y; o.z = a.z + bv.z; o.w = a.w + bv.w;
        *reinterpret_cast<float4*>(&out[(size_t)rowBase * OUT_F + i * 4]) = o;
    }
}

// ---------------------------------------------------------------------------
// Fallback path (ws too small): round-1 atomic scatter
// ---------------------------------------------------------------------------
__global__ __launch_bounds__(256) void gcn_bias_init(const float* __restrict__ bias,
                                                     float* __restrict__ out) {
    const int i = blockIdx.x * 256 + threadIdx.x;
    if (i < N_NODES * OUT_F) out[i] = bias[i & 31];
}

__global__ __launch_bounds__(256) void gcn_scatter(const int* __restrict__ row,
                                                   const int* __restrict__ col,
                                                   const float* __restrict__ val,
                                                   const float* __restrict__ support,
                                                   float* __restrict__ out) {
    const int f = threadIdx.x & 31;
    const int grp = threadIdx.x >> 5;
    long long e = (long long)blockIdx.x * 8 + grp;
    const long long stride = (long long)gridDim.x * 8;
    for (; e < N_EDGES; e += stride) {
        const int r = row[e];
        const int c = col[e];
        const float v = val[e];
        const float s = support[(size_t)c * OUT_F + f];
        atomicAdd(&out[(size_t)r * OUT_F + f], v * s);
    }
}

extern "C" void kernel_launch(void* const* d_in, const int* in_sizes, int n_in,
                              void* d_out, int out_size, void* d_ws, size_t ws_size,
                              hipStream_t stream) {
    const float* x       = (const float*)d_in[0];
    const int*   adj_row = (const int*)d_in[1];
    const int*   adj_col = (const int*)d_in[2];
    const float* adj_val = (const float*)d_in[3];
    const float* weight  = (const float*)d_in[4];
    const float* bias    = (const float*)d_in[5];
    float* out = (float*)d_out;

    char* ws = (char*)d_ws;
    const size_t SUPPORT_B = (size_t)N_NODES * OUT_F * 4;     // 12,800,000
    const size_t REC_B     = (size_t)N_EDGES * 8;             // 12,800,000
    const size_t CNT_B     = ((size_t)NTOT * 4 + 255) & ~(size_t)255;  // ~800,768
    const size_t BSUM_B    = ((size_t)NBLK_SCAN * 4 + 255) & ~(size_t)255;
    const size_t NEED = SUPPORT_B + REC_B + 2 * CNT_B + BSUM_B;

    float* support  = (float*)(ws);
    long long* rec  = (long long*)(ws + SUPPORT_B);
    int* count      = (int*)(ws + SUPPORT_B + REC_B);
    int* ptr        = (int*)(ws + SUPPORT_B + REC_B + CNT_B);
    int* bsum       = (int*)(ws + SUPPORT_B + REC_B + 2 * CNT_B);

    // 1) support = x @ W
    gcn_gemm2<<<(N_NODES + 63) / 64, 256, 0, stream>>>(x, weight, support);

    if (ws_size >= NEED) {
        // 2) blocked multisplit: count -> scan(3-phase) -> bin
        gcn_count<<<ABLK, 256, 0, stream>>>(adj_row, count);
        scan_a<<<NBLK_SCAN, 256, 0, stream>>>(count, ptr, bsum);
        scan_b<<<1, 1024, 0, stream>>>(bsum);
        scan_c<<<NBLK_SCAN, 256, 0, stream>>>(ptr, bsum);
        gcn_bin<<<ABLK, 256, 0, stream>>>(adj_row, adj_col, adj_val, ptr, rec);
        // 3) per-bucket batched LDS accumulation, bias fused
        gcn_acc<<<NB, 256, 0, stream>>>(ptr, rec, support, bias, out);
    } else {
        // Fallback: atomic scatter path
        gcn_bias_init<<<(N_NODES * OUT_F + 255) / 256, 256, 0, stream>>>(bias, out);
        gcn_scatter<<<8192, 256, 0, stream>>>(adj_row, adj_col, adj_val, support, out);
    }
}